// Round 9
// baseline (492.383 us; speedup 1.0000x reference)
//
#include <hip/hip_runtime.h>

// x: (64,3,512,512) fp32 -> conv3x3 VALID + avgpool2x2 + sigmoid + per-batch sum.
// Fused stride-2 4x4 conv: w_eff[ky][kx] = 0.25*sum_{py,px in {0,1}} w[ky-py][kx-px].
//
// R8 = R7's allocator-proof streaming structure + R2's packed v2f math + fine grid.
//  Empirical law (R2 vs R7 calibration): dur ~ VALU-inst-count x 2.9 / busy-frac.
//  R7 fixed stalls (VALU 35->68%) but doubled insts (scalar); R2 had packed math
//  but stalled. This round: both.
//   - lane = pooled col-pair; acc = 8 oc x v2f{colA,colB} x {role-swapped pair}
//     = 32 floats persistent. Weights wave-uniform s_load scalars (broadcast into
//     v_pk_fma_f32). x float4+float2 per (par,ic), consumed immediately.
//   - oc in 2 chunks (blockIdx.x); chunk-1 pass is L3-resident (VERIFIED R7:
//     FETCH stayed ~1x input).
//   - L=5/STRIPS=51: 6528 blocks -> ~12 waves/SIMD available (R7's 24.5% occ was
//     grid-starved at 2176 blocks). Cost: 1.2x row halo, L3-absorbed.

#define IC 3
#define OCH 16
#define OCC 8       // oc per chunk
#define HH 512
#define WW 512
#define WP 255      // pooled cols
#define L 5         // pooled rows per strip (255 = 5*51)
#define STRIPS 51

typedef float v2f __attribute__((ext_vector_type(2)));

__device__ __forceinline__ float fast_sigmoid(float v) {
    float e = __expf(-v);                    // v_exp_f32
    return __builtin_amdgcn_rcpf(1.0f + e);  // v_rcp_f32
}

// ws layout (floats) — same as R7 (verified):
//   12 blocks of 64: blk = (chunk*2+par)*3+ic
//     blk[oc8*8 + 0..3] = w_eff[par+2][ic][kx]  ("old": completes pooled row)
//     blk[oc8*8 + 4..7] = w_eff[par  ][ic][kx]  ("new": starts pooled row)
//   bias at ws[768 + oc]   (total 784 floats)
__global__ void build_weff(const float* __restrict__ w,
                           const float* __restrict__ bias,
                           float* __restrict__ ws)
{
    const int i = threadIdx.x;
    for (int idx = i; idx < 768; idx += 256) {
        const int blk   = idx >> 6;       // (chunk*2+par)*3+ic
        const int r     = idx & 63;
        const int oc8   = r >> 3;
        const int which = (r >> 2) & 1;   // 0: old (ky=par+2), 1: new (ky=par)
        const int kx    = r & 3;
        const int ic    = blk % 3;
        const int t2    = blk / 3;        // chunk*2+par
        const int par   = t2 & 1;
        const int chunk = t2 >> 1;
        const int oc    = chunk * OCC + oc8;
        const int ky    = which ? par : (par + 2);
        float s = 0.f;
#pragma unroll
        for (int py = 0; py < 2; ++py) {
            int rr = ky - py;
            if (rr < 0 || rr > 2) continue;
#pragma unroll
            for (int px = 0; px < 2; ++px) {
                int cc = kx - px;
                if (cc < 0 || cc > 2) continue;
                s += w[((oc * IC + ic) * 3 + rr) * 3 + cc];
            }
        }
        ws[idx] = 0.25f * s;
    }
    if (i < OCH) ws[768 + i] = bias[i];
}

// One t-step: input rows 2T,2T+1. AO completes (pooled row T-1), AN starts
// (pooled row T). Packed over the lane's two pooled cols:
//   col A uses x[0..3] = a.xyzw ; col B uses x[2..5] = a.z,a.w,tv.x,tv.y
//   xp[kx] = {x[kx], x[kx+2]} ; acc += xp[kx] * w_scalar  (v_pk_fma_f32)
#define STEP(T, AO, AN, EMIT)                                               \
  {                                                                         \
    _Pragma("unroll")                                                       \
    for (int par = 0; par < 2; ++par) {                                     \
      _Pragma("unroll")                                                     \
      for (int ic = 0; ic < IC; ++ic) {                                     \
        const float* xp = xg + (size_t)ic * (HH * WW)                       \
                             + (size_t)(2 * (T) + par) * WW;                \
        const float4 a  = *(const float4*)xp;                               \
        const float2 tv = *(const float2*)(xp + tail);                      \
        const v2f x0 = {a.x, a.z};                                          \
        const v2f x1 = {a.y, a.w};                                          \
        const v2f x2 = {a.z, tv.x};                                         \
        const v2f x3 = {a.w, tv.y};                                         \
        const float* wb = wbase + (par * IC + ic) * 64;                     \
        _Pragma("unroll")                                                   \
        for (int o = 0; o < OCC; ++o) {                                     \
          AO[o] += x0 * wb[o*8+0];                                          \
          AO[o] += x1 * wb[o*8+1];                                          \
          AO[o] += x2 * wb[o*8+2];                                          \
          AO[o] += x3 * wb[o*8+3];                                          \
          AN[o] += x0 * wb[o*8+4];                                          \
          AN[o] += x1 * wb[o*8+5];                                          \
          AN[o] += x2 * wb[o*8+6];                                          \
          AN[o] += x3 * wb[o*8+7];                                          \
        }                                                                   \
      }                                                                     \
    }                                                                       \
    if (EMIT) {                                                             \
      _Pragma("unroll")                                                     \
      for (int o = 0; o < OCC; ++o) {                                       \
        lsA += fast_sigmoid(AO[o].x);                                       \
        lsB += fast_sigmoid(AO[o].y);                                       \
      }                                                                     \
    }                                                                       \
    _Pragma("unroll")                                                       \
    for (int o = 0; o < OCC; ++o) AO[o] = (v2f){bv[o], bv[o]};              \
  }

__global__ __launch_bounds__(128, 4)
void conv_pool_sig_sum(const float* __restrict__ x,
                       const float* __restrict__ wws,
                       float* __restrict__ out)
{
    const int tid   = threadIdx.x;             // 0..127: pooled cols 2tid, 2tid+1
    const int chunk = blockIdx.x;              // 0,1: oc chunk (L3 reuse on 2nd)
    const int b     = blockIdx.y;
    const int r0    = blockIdx.z * L;
    const int tail  = (tid < 127) ? 4 : 0;     // lane 127: re-read in-bounds, masked

    const float* xg = x + (size_t)b * (IC * HH * WW)
                        + (size_t)(2 * r0) * WW + 4 * tid;
    const float* wbase = wws + chunk * (2 * IC * 64);

    float bv[OCC];
#pragma unroll
    for (int o = 0; o < OCC; ++o) bv[o] = wws[768 + chunk * OCC + o];

    // persistent state: 2 x 8 v2f accumulators (32 floats) + 8 bias
    v2f aX[OCC], aY[OCC];
#pragma unroll
    for (int o = 0; o < OCC; ++o) {
        aX[o] = (v2f){bv[o], bv[o]};
        aY[o] = (v2f){bv[o], bv[o]};
    }
    float lsA = 0.f, lsB = 0.f;

    // 6 steps (t=0..5): step t reads input rows 2(r0+t), +1.
    // t=0: aX's "old" half is garbage -> not emitted, reinit'd. Final step's
    // "new" half (next strip's first pooled row) is dropped after the loop.
#pragma unroll 1
    for (int t = 0; t < L + 1; t += 2) {
        STEP(t,     aX, aY, (t > 0))
        STEP(t + 1, aY, aX, true)
    }

    if (2 * tid + 1 >= WP) lsB = 0.f;   // pooled col 255 doesn't exist (lane 127)
    float lsum = lsA + lsB;

    // wave64 butterfly -> 2-wave LDS reduce -> one atomic per block
#pragma unroll
    for (int off = 32; off > 0; off >>= 1)
        lsum += __shfl_xor(lsum, off, 64);

    __shared__ float red[2];
    if ((tid & 63) == 0) red[tid >> 6] = lsum;
    __syncthreads();
    if (tid == 0) atomicAdd(out + b, red[0] + red[1]);
}

extern "C" void kernel_launch(void* const* d_in, const int* in_sizes, int n_in,
                              void* d_out, int out_size, void* d_ws, size_t ws_size,
                              hipStream_t stream) {
    const float* x = (const float*)d_in[0];
    const float* w = (const float*)d_in[1];
    const float* bias = (const float*)d_in[2];
    float* out = (float*)d_out;
    float* wws = (float*)d_ws;  // 784 floats

    hipMemsetAsync(out, 0, out_size * sizeof(float), stream);
    build_weff<<<1, 256, 0, stream>>>(w, bias, wws);

    dim3 grid(2, 64, STRIPS);  // 2 oc-chunks x 64 batches x 51 strips = 6528 blocks
    conv_pool_sig_sum<<<grid, 128, 0, stream>>>(x, wws, out);
}

// Round 10
// 327.885 us; speedup vs baseline: 1.5017x; 1.5017x over previous
//
#include <hip/hip_runtime.h>

// x: (64,3,512,512) fp32 -> conv3x3 VALID + avgpool2x2 + sigmoid + per-batch sum.
// Fused stride-2 4x4 conv: w_eff[ky][kx] = 0.25*sum_{py,px in {0,1}} w[ky-py][kx-px].
//
// R9 = R2 (measured best, 167us) + two minimal edits:
//  (1) asm-pin the 72-float x window after load (forces VGPR residency; defeats
//      the allocator's load-sinking that made R2 re-read x 16x per srow from L1
//      -- the VGPR=68 tell). Rematerialization is illegal once the value passes
//      through an opaque "+v" asm.
//  (2) #pragma unroll 2 on the oc loop so adjacent oc's s_load weight blocks
//      pipeline (R2's unroll 1 serialized s_load-wait -> FMA 16x per srow).
//  Everything else is byte-identical to R2. Ledger: R2 busy-time 59us @ 35%
//  duty; this targets same stream at 55-65% duty.

#define IC 3
#define OCH 16
#define HH 512
#define WW 512
#define HP 255
#define SROWS 5
#define STRIPS 51  // 51 * 5 = 255 pooled rows

typedef float v2f __attribute__((ext_vector_type(2)));

__device__ __forceinline__ float fast_sigmoid(float v) {
    float e = __expf(-v);                    // v_exp_f32
    return __builtin_amdgcn_rcpf(1.0f + e);  // v_rcp_f32
}

// d_ws layout: per oc, 64 floats: [48 w_eff, idx = ic*16 + ky*4 + kx][bias][15 pad]
// (256 B stride keeps s_load_dwordx16 64B-aligned)
__global__ void build_weff(const float* __restrict__ w,
                           const float* __restrict__ bias,
                           float* __restrict__ ws)
{
    const int i = threadIdx.x;
    for (int idx = i; idx < OCH * 48; idx += 256) {
        int oc = idx / 48;
        int rem = idx - oc * 48;
        int ic = rem >> 4;
        int ky = (rem >> 2) & 3;
        int kx = rem & 3;
        float s = 0.f;
#pragma unroll
        for (int py = 0; py < 2; ++py) {
            int r = ky - py;
            if (r < 0 || r > 2) continue;
#pragma unroll
            for (int px = 0; px < 2; ++px) {
                int c = kx - px;
                if (c < 0 || c > 2) continue;
                s += w[((oc * IC + ic) * 3 + r) * 3 + c];
            }
        }
        ws[oc * 64 + rem] = 0.25f * s;
    }
    if (i < OCH) ws[i * 64 + 48] = bias[i];
}

__global__ __launch_bounds__(128)
void conv_pool_sig_sum(const float* __restrict__ x,
                       const float* __restrict__ wws,
                       float* __restrict__ out)
{
    const int tid = threadIdx.x;      // 0..127 == pooled-col-pair index
    const bool v1 = (tid < 127);      // pooled col 2*127+1 = 255 doesn't exist
    const int c0 = 4 * tid;           // input col base (max 508)
    const int b = blockIdx.y;
    const int hp0 = blockIdx.x * SROWS;
    const int tail = v1 ? 4 : 0;      // right edge: re-read in-bounds, masked later

    const float* xb = x + ((size_t)b * IC * HH + (size_t)2 * hp0) * WW + c0;

    float lsum = 0.f, lsum1 = 0.f;

    for (int s = 0; s < SROWS; ++s) {
        // Load the 4x6 window for all 3 ic ONCE (72 floats in VGPRs),
        // reused across all 16 output channels.
        float4 xa[IC][4];
        float2 xt[IC][4];
#pragma unroll
        for (int ic = 0; ic < IC; ++ic) {
            const float* pr = xb + (size_t)ic * HH * WW;
#pragma unroll
            for (int r = 0; r < 4; ++r) {
                xa[ic][r] = *(const float4*)(pr + r * WW);         // cols c0..c0+3
                xt[ic][r] = *(const float2*)(pr + r * WW + tail);  // cols c0+4..c0+5
            }
        }
        // PIN the window: once a value passes through an opaque "+v" asm, the
        // compiler cannot re-materialize the load -> stays resident in VGPRs.
#pragma unroll
        for (int ic = 0; ic < IC; ++ic)
#pragma unroll
            for (int r = 0; r < 4; ++r) {
                asm volatile("" : "+v"(xa[ic][r].x), "+v"(xa[ic][r].y),
                                  "+v"(xa[ic][r].z), "+v"(xa[ic][r].w));
                asm volatile("" : "+v"(xt[ic][r].x), "+v"(xt[ic][r].y));
            }

        // oc loop unrolled x2: adjacent oc's s_load weight blocks pipeline,
        // SMEM latency hides under the previous oc's 48 packed FMAs.
#pragma unroll 2
        for (int oc = 0; oc < OCH; ++oc) {
            const float* we = wws + oc * 64;   // wave-uniform address -> s_load
            const float bv = we[48];
            v2f acc = {bv, bv};
#pragma unroll
            for (int ic = 0; ic < IC; ++ic) {
#pragma unroll
                for (int r = 0; r < 4; ++r) {
                    const float4 a = xa[ic][r];
                    const float2 t = xt[ic][r];
                    const float* wr = we + ic * 16 + r * 4;
                    acc += (v2f){a.x, a.z} * wr[0];
                    acc += (v2f){a.y, a.w} * wr[1];
                    acc += (v2f){a.z, t.x} * wr[2];
                    acc += (v2f){a.w, t.y} * wr[3];
                }
            }
            lsum  += fast_sigmoid(acc.x);
            lsum1 += fast_sigmoid(acc.y);
        }
        xb += 2 * WW;
    }
    lsum += v1 ? lsum1 : 0.f;

    // wave64 butterfly, one atomic per wave (2 per block)
#pragma unroll
    for (int off = 32; off > 0; off >>= 1)
        lsum += __shfl_xor(lsum, off, 64);
    if ((tid & 63) == 0) atomicAdd(out + b, lsum);
}

extern "C" void kernel_launch(void* const* d_in, const int* in_sizes, int n_in,
                              void* d_out, int out_size, void* d_ws, size_t ws_size,
                              hipStream_t stream) {
    const float* x = (const float*)d_in[0];
    const float* w = (const float*)d_in[1];
    const float* bias = (const float*)d_in[2];
    float* out = (float*)d_out;
    float* wws = (float*)d_ws;  // 16 * 64 floats = 4 KB

    hipMemsetAsync(out, 0, out_size * sizeof(float), stream);
    build_weff<<<1, 256, 0, stream>>>(w, bias, wws);

    dim3 grid(STRIPS, 64);  // 51 row-strips x 64 batches = 3264 blocks
    conv_pool_sig_sum<<<grid, 128, 0, stream>>>(x, wws, out);
}